// Round 1
// baseline (516.389 us; speedup 1.0000x reference)
//
#include <hip/hip_runtime.h>

#define NV_N 32
#define NV_C 128
#define NV_K 64
#define NV_S 12544
#define ST 64          // s-tile width
#define TILES 14       // s-tiles per block
#define SCHUNK 14      // blocks per image; 14*14*64 = 12544
#define XSTR 68        // x_lds row stride (floats), pad vs 64 to break bank conflicts
#define ASTR 68        // a_lds row stride (ushorts)
#define WSTR 132       // w_lds row stride (ushorts), pad vs 128

static __device__ __forceinline__ unsigned short f2bf(float f) {
  union { float f; unsigned u; } v; v.f = f;
  unsigned r = v.u + 0x7FFFu + ((v.u >> 16) & 1u);  // RNE
  return (unsigned short)(r >> 16);
}
static __device__ __forceinline__ float bf2f(unsigned short h) {
  union { unsigned u; float f; } v; v.u = ((unsigned)h) << 16; return v.f;
}
static __device__ __forceinline__ float bflo(unsigned p) {
  union { unsigned u; float f; } v; v.u = p << 16; return v.f;
}
static __device__ __forceinline__ float bfhi(unsigned p) {
  union { unsigned u; float f; } v; v.u = p & 0xFFFF0000u; return v.f;
}

__global__ __launch_bounds__(256, 1) void netvlad_main(
    const float* __restrict__ x, const float* __restrict__ conv_w,
    float* __restrict__ vlad_ws, float* __restrict__ asum_ws) {
  __shared__ unsigned short w_lds[NV_K * WSTR];  // 16896 B (bf16 weights)
  __shared__ float          x_lds[NV_C * XSTR];  // 34816 B (fp32 x tile)
  __shared__ unsigned short a_lds[NV_K * ASTR];  //  8704 B (bf16 logits->assign)
  __shared__ float          red1[4 * 64];
  __shared__ float          red2[4 * 64];
  __shared__ float          asum_lds[NV_K];
  // total LDS = 62720 B

  const int t = threadIdx.x;
  const int n = blockIdx.x / SCHUNK;
  const int chunk = blockIdx.x % SCHUNK;
  const int s_blk = chunk * (ST * TILES);

  // stage conv_w -> LDS (bf16)
#pragma unroll
  for (int i = 0; i < 8; ++i) {
    int vec = t + i * 256;           // 2048 float4 groups
    int k = vec >> 5; int cq = vec & 31;
    float4 wv = *(const float4*)(conv_w + k * NV_C + cq * 4);
    ushort4 hv;
    hv.x = f2bf(wv.x); hv.y = f2bf(wv.y); hv.z = f2bf(wv.z); hv.w = f2bf(wv.w);
    *(ushort4*)&w_lds[k * WSTR + cq * 4] = hv;
  }
  if (t < NV_K) asum_lds[t] = 0.0f;

  const int kg  = t >> 4;        // 0..15
  const int sg  = t & 15;        // 0..15
  const int k0  = kg * 4;        // 4 clusters per thread
  const int s0c = sg * 4;        // 4 s-columns per thread (GEMM1)
  const int cq  = t & 15;        // GEMM2: c = cq + 16*j

  float acc2[4][8];
#pragma unroll
  for (int i = 0; i < 4; ++i)
#pragma unroll
    for (int j = 0; j < 8; ++j) acc2[i][j] = 0.0f;

  const float* xn = x + (long)n * NV_C * NV_S;

  for (int tt = 0; tt < TILES; ++tt) {
    const int s0 = s_blk + tt * ST;
    __syncthreads();  // previous tile fully consumed before overwriting x_lds

    // ---- stage x tile (fp32, coalesced float4) ----
#pragma unroll
    for (int i = 0; i < 8; ++i) {
      int vec = t + i * 256;
      int c = vec >> 4; int sv = vec & 15;
      float4 xv = *(const float4*)(xn + (long)c * NV_S + s0 + sv * 4);
      *(float4*)&x_lds[c * XSTR + sv * 4] = xv;
    }
    __syncthreads();

    // ---- GEMM1: logits[k][s] = sum_c w[k][c] * x[c][s]  (4k x 4s per thread) ----
    float acc1[4][4];
#pragma unroll
    for (int i = 0; i < 4; ++i)
#pragma unroll
      for (int j = 0; j < 4; ++j) acc1[i][j] = 0.0f;

#pragma unroll 2
    for (int c2 = 0; c2 < NV_C / 2; ++c2) {
      const float4 xa = *(const float4*)&x_lds[(2 * c2 + 0) * XSTR + s0c];
      const float4 xb = *(const float4*)&x_lds[(2 * c2 + 1) * XSTR + s0c];
#pragma unroll
      for (int i = 0; i < 4; ++i) {
        const unsigned wp = *(const unsigned*)&w_lds[(k0 + i) * WSTR + 2 * c2];
        const float wa = bflo(wp), wb = bfhi(wp);
        acc1[i][0] += wa * xa.x + wb * xb.x;
        acc1[i][1] += wa * xa.y + wb * xb.y;
        acc1[i][2] += wa * xa.z + wb * xb.z;
        acc1[i][3] += wa * xa.w + wb * xb.w;
      }
    }
#pragma unroll
    for (int i = 0; i < 4; ++i) {
      ushort4 hv;
      hv.x = f2bf(acc1[i][0]); hv.y = f2bf(acc1[i][1]);
      hv.z = f2bf(acc1[i][2]); hv.w = f2bf(acc1[i][3]);
      *(ushort4*)&a_lds[(k0 + i) * ASTR + s0c] = hv;
    }
    __syncthreads();

    // ---- softmax over k per column s (4 threads per column) ----
    {
      const int q = t >> 6; const int s = t & 63; const int kb = q * 16;
      float m = -1e30f;
#pragma unroll
      for (int i = 0; i < 16; ++i) m = fmaxf(m, bf2f(a_lds[(kb + i) * ASTR + s]));
      red1[q * 64 + s] = m;
      __syncthreads();
      m = fmaxf(fmaxf(red1[s], red1[64 + s]), fmaxf(red1[128 + s], red1[192 + s]));
      float sum = 0.0f;
#pragma unroll
      for (int i = 0; i < 16; ++i) {
        float e = __expf(bf2f(a_lds[(kb + i) * ASTR + s]) - m);
        sum += e;
        a_lds[(kb + i) * ASTR + s] = f2bf(e);
      }
      red2[q * 64 + s] = sum;
      __syncthreads();
      const float inv = 1.0f / (red2[s] + red2[64 + s] + red2[128 + s] + red2[192 + s]);
#pragma unroll
      for (int i = 0; i < 16; ++i) {
        float a = bf2f(a_lds[(kb + i) * ASTR + s]) * inv;
        a_lds[(kb + i) * ASTR + s] = f2bf(a);
      }
    }
    __syncthreads();

    // ---- asum partials (row sums of a) ----
    {
      const int k = t & 63; const int g = t >> 6;
      float p = 0.0f;
#pragma unroll
      for (int i = 0; i < 16; ++i) p += bf2f(a_lds[k * ASTR + g * 16 + i]);
      red1[g * 64 + k] = p;
    }

    // ---- GEMM2: vlad[k][c] += a[k][s] * x[c][s]  (4k x 8c per thread) ----
#pragma unroll 2
    for (int s2 = 0; s2 < ST / 2; ++s2) {
      const int s = 2 * s2;
      float aa[4], ab[4];
#pragma unroll
      for (int i = 0; i < 4; ++i) {
        const unsigned ap = *(const unsigned*)&a_lds[(k0 + i) * ASTR + s];
        aa[i] = bflo(ap); ab[i] = bfhi(ap);
      }
#pragma unroll
      for (int j = 0; j < 8; ++j) {
        const float2 xp = *(const float2*)&x_lds[(cq + 16 * j) * XSTR + s];
#pragma unroll
        for (int i = 0; i < 4; ++i)
          acc2[i][j] += aa[i] * xp.x + ab[i] * xp.y;
      }
    }
    __syncthreads();
    if (t < NV_K)
      asum_lds[t] += red1[t] + red1[64 + t] + red1[128 + t] + red1[192 + t];
  }

  __syncthreads();
  float* vw = vlad_ws + (long)n * (NV_K * NV_C);
#pragma unroll
  for (int i = 0; i < 4; ++i)
#pragma unroll
    for (int j = 0; j < 8; ++j)
      atomicAdd(vw + (k0 + i) * NV_C + cq + 16 * j, acc2[i][j]);
  if (t < NV_K) atomicAdd(asum_ws + (long)n * NV_K + t, asum_lds[t]);
}

__global__ __launch_bounds__(256) void netvlad_finalize(
    const float* __restrict__ vlad_ws, const float* __restrict__ asum_ws,
    const float* __restrict__ cent, float* __restrict__ out) {
  __shared__ float v_lds[NV_K * NV_C];  // 32 KB
  __shared__ float red4[256];
  __shared__ float rscale[NV_K];
  __shared__ float gscale_sh;

  const int t = threadIdx.x; const int n = blockIdx.x;
  const float* vw = vlad_ws + (long)n * (NV_K * NV_C);

#pragma unroll
  for (int i = 0; i < 8; ++i) {
    int vec = t + i * 256; int k = vec >> 5; int cq = vec & 31;
    float4 ws = *(const float4*)(vw + k * NV_C + cq * 4);
    float4 ce = *(const float4*)(cent + k * NV_C + cq * 4);
    float as = asum_ws[(long)n * NV_K + k];
    float4 v;
    v.x = ws.x - as * ce.x; v.y = ws.y - as * ce.y;
    v.z = ws.z - as * ce.z; v.w = ws.w - as * ce.w;
    *(float4*)&v_lds[k * NV_C + cq * 4] = v;
  }
  __syncthreads();

  {  // per-row (cluster) sumsq
    const int k = t >> 2, part = t & 3;
    const float* row = &v_lds[k * NV_C + part * 32];
    float ss = 0.0f;
#pragma unroll
    for (int c = 0; c < 32; ++c) { float v = row[c]; ss += v * v; }
    red4[t] = ss;
  }
  __syncthreads();
  if (t < NV_K) {
    float ss = red4[t * 4] + red4[t * 4 + 1] + red4[t * 4 + 2] + red4[t * 4 + 3];
    rscale[t] = 1.0f / fmaxf(sqrtf(ss), 1e-12f);
  }
  __syncthreads();

  float gp = 0.0f;
#pragma unroll
  for (int i = 0; i < 8; ++i) {
    int vec = t + i * 256; int k = vec >> 5; int cq = vec & 31;
    float4 v = *(const float4*)&v_lds[k * NV_C + cq * 4];
    float rs = rscale[k];
    gp += (v.x * v.x + v.y * v.y + v.z * v.z + v.w * v.w) * rs * rs;
  }
  red4[t] = gp;
  __syncthreads();
  if (t < 64) {
    float s = red4[t] + red4[t + 64] + red4[t + 128] + red4[t + 192];
#pragma unroll
    for (int o = 32; o > 0; o >>= 1) s += __shfl_down(s, o);
    if (t == 0) gscale_sh = 1.0f / fmaxf(sqrtf(s), 1e-12f);
  }
  __syncthreads();
  const float gs = gscale_sh;

#pragma unroll
  for (int i = 0; i < 8; ++i) {
    int vec = t + i * 256; int k = vec >> 5; int cq = vec & 31;
    float4 v = *(const float4*)&v_lds[k * NV_C + cq * 4];
    const float sc = rscale[k] * gs;
    v.x *= sc; v.y *= sc; v.z *= sc; v.w *= sc;
    *(float4*)(out + (long)n * (NV_K * NV_C) + k * NV_C + cq * 4) = v;
  }
}

extern "C" void kernel_launch(void* const* d_in, const int* in_sizes, int n_in,
                              void* d_out, int out_size, void* d_ws, size_t ws_size,
                              hipStream_t stream) {
  (void)in_sizes; (void)n_in; (void)out_size; (void)ws_size;
  const float* x      = (const float*)d_in[0];
  const float* conv_w = (const float*)d_in[1];
  const float* cent   = (const float*)d_in[2];
  float* out = (float*)d_out;

  float* vlad_ws = (float*)d_ws;
  float* asum_ws = vlad_ws + (size_t)NV_N * NV_K * NV_C;
  const size_t zbytes = ((size_t)NV_N * NV_K * NV_C + (size_t)NV_N * NV_K) * sizeof(float);
  hipMemsetAsync(d_ws, 0, zbytes, stream);

  hipLaunchKernelGGL(netvlad_main, dim3(NV_N * SCHUNK), dim3(256), 0, stream,
                     x, conv_w, vlad_ws, asum_ws);
  hipLaunchKernelGGL(netvlad_finalize, dim3(NV_N), dim3(256), 0, stream,
                     vlad_ws, asum_ws, cent, out);
}

// Round 2
// 299.505 us; speedup vs baseline: 1.7241x; 1.7241x over previous
//
#include <hip/hip_runtime.h>

#define NV_N 32
#define NV_C 128
#define NV_K 64
#define NV_S 12544
#define ST 64          // s-columns per tile
#define TILES 14       // tiles per block
#define SCHUNK 14      // blocks per image
#define XS 72          // x_lds row stride (bf16 elems), 144 B: 16B-aligned rows
#define AS 72          // a_lds row stride

typedef short short8 __attribute__((ext_vector_type(8)));
typedef float floatx4 __attribute__((ext_vector_type(4)));

static __device__ __forceinline__ unsigned short f2bf(float f) {
  union { float f; unsigned u; } v; v.f = f;
  unsigned r = v.u + 0x7FFFu + ((v.u >> 16) & 1u);  // RNE
  return (unsigned short)(r >> 16);
}

static __device__ __forceinline__ short8 pack8(float4 a, float4 b) {
  union { unsigned short us[8]; short8 s; } u;
  u.us[0] = f2bf(a.x); u.us[1] = f2bf(a.y); u.us[2] = f2bf(a.z); u.us[3] = f2bf(a.w);
  u.us[4] = f2bf(b.x); u.us[5] = f2bf(b.y); u.us[6] = f2bf(b.z); u.us[7] = f2bf(b.w);
  return u.s;
}

__global__ __launch_bounds__(256, 2) void netvlad_main(
    const float* __restrict__ x, const float* __restrict__ conv_w,
    float* __restrict__ vlad_ws, float* __restrict__ asum_ws) {
  __shared__ __attribute__((aligned(16))) unsigned short x_lds[2][NV_C * XS]; // 36864 B
  __shared__ __attribute__((aligned(16))) unsigned short a_lds[NV_K * AS];    //  9216 B
  __shared__ float asum_sh[4][NV_K];                                          //  1024 B

  const int t = threadIdx.x;
  const int n = blockIdx.x / SCHUNK;
  const int chunk = blockIdx.x % SCHUNK;
  const int s_base = chunk * (ST * TILES);
  const int w = t >> 6;        // wave 0..3
  const int lane = t & 63;
  const int q = lane >> 4;     // quad 0..3
  const int l = lane & 15;

  const float* __restrict__ xn = x + (size_t)n * NV_C * NV_S;

  // ---- preload W as A-operand fragments: wfrag[mt][kc], lane holds W[mt*16+l][kc*32+q*8+j] ----
  short8 wfrag[4][4];
#pragma unroll
  for (int mt = 0; mt < 4; ++mt)
#pragma unroll
    for (int kc = 0; kc < 4; ++kc) {
      const float* wp = conv_w + (mt * 16 + l) * NV_C + kc * 32 + q * 8;
      float4 wa = *(const float4*)wp;
      float4 wb = *(const float4*)(wp + 4);
      wfrag[mt][kc] = pack8(wa, wb);
    }

  floatx4 acc2[4][2];   // vlad accumulators: [mt][nt], k=mt*16+q*4+r, c=(w*2+nt)*16+l
  float asum_acc[4][4]; // per-lane asum partials for k = mt*16+q*4+r
#pragma unroll
  for (int mt = 0; mt < 4; ++mt) {
#pragma unroll
    for (int nt = 0; nt < 2; ++nt) acc2[mt][nt] = (floatx4){0.f, 0.f, 0.f, 0.f};
#pragma unroll
    for (int r = 0; r < 4; ++r) asum_acc[mt][r] = 0.f;
  }

  float4 pf[8];  // prefetch registers: 4 groups x 2 float4 (8 consecutive s each)

  // prefetch tile 0
  {
#pragma unroll
    for (int g = 0; g < 4; ++g) {
      int vec2 = t + g * 256; int c = vec2 >> 3; int sv8 = vec2 & 7;
      const float* p = xn + (size_t)c * NV_S + s_base + sv8 * 8;
      pf[2 * g] = *(const float4*)p;
      pf[2 * g + 1] = *(const float4*)(p + 4);
    }
  }

  for (int tt = 0; tt < TILES; ++tt) {
    const int buf = tt & 1;
    // ---- convert + write staged tile to LDS (bf16) ----
#pragma unroll
    for (int g = 0; g < 4; ++g) {
      int vec2 = t + g * 256; int c = vec2 >> 3; int sv8 = vec2 & 7;
      *(short8*)&x_lds[buf][c * XS + sv8 * 8] = pack8(pf[2 * g], pf[2 * g + 1]);
    }
    __syncthreads();

    // ---- issue prefetch for tile tt+1 (consumed next iteration) ----
    if (tt + 1 < TILES) {
      const int s0n = s_base + (tt + 1) * ST;
#pragma unroll
      for (int g = 0; g < 4; ++g) {
        int vec2 = t + g * 256; int c = vec2 >> 3; int sv8 = vec2 & 7;
        const float* p = xn + (size_t)c * NV_S + s0n + sv8 * 8;
        pf[2 * g] = *(const float4*)p;
        pf[2 * g + 1] = *(const float4*)(p + 4);
      }
    }

    // ---- GEMM1: logits[64 k][16 s(wave)] = W(64x128) * x(128x64-tile) ----
    floatx4 acc1[4];
#pragma unroll
    for (int mt = 0; mt < 4; ++mt) acc1[mt] = (floatx4){0.f, 0.f, 0.f, 0.f};
#pragma unroll
    for (int kc = 0; kc < 4; ++kc) {
      // B-frag: B[c][s], lane needs x[kc*32+q*8+j][w*16+l] -> 8 strided u16 reads
      short8 bfr;
#pragma unroll
      for (int j = 0; j < 8; ++j)
        bfr[j] = (short)x_lds[buf][(kc * 32 + q * 8 + j) * XS + w * 16 + l];
#pragma unroll
      for (int mt = 0; mt < 4; ++mt)
        acc1[mt] = __builtin_amdgcn_mfma_f32_16x16x32_bf16(wfrag[mt][kc], bfr, acc1[mt], 0, 0, 0);
    }

    // ---- softmax over k (64) per column s; all in registers ----
    {
      float m = -1e30f;
#pragma unroll
      for (int mt = 0; mt < 4; ++mt)
#pragma unroll
        for (int r = 0; r < 4; ++r) m = fmaxf(m, acc1[mt][r]);
      m = fmaxf(m, __shfl_xor(m, 16));
      m = fmaxf(m, __shfl_xor(m, 32));
      float sum = 0.f;
#pragma unroll
      for (int mt = 0; mt < 4; ++mt)
#pragma unroll
        for (int r = 0; r < 4; ++r) {
          float e = __expf(acc1[mt][r] - m);
          acc1[mt][r] = e; sum += e;
        }
      sum += __shfl_xor(sum, 16);
      sum += __shfl_xor(sum, 32);
      const float inv = 1.0f / sum;
#pragma unroll
      for (int mt = 0; mt < 4; ++mt)
#pragma unroll
        for (int r = 0; r < 4; ++r) {
          float a = acc1[mt][r] * inv;
          asum_acc[mt][r] += a;
          a_lds[(mt * 16 + q * 4 + r) * AS + w * 16 + l] = f2bf(a);
        }
    }
    __syncthreads();

    // ---- GEMM2: vlad[64 k][128 c] += a(64 x 64s) * x^T(64s x 128c) ----
#pragma unroll
    for (int sk = 0; sk < 2; ++sk) {
      short8 afr[4];
#pragma unroll
      for (int mt = 0; mt < 4; ++mt)
        afr[mt] = *(const short8*)&a_lds[(mt * 16 + l) * AS + sk * 32 + q * 8];
#pragma unroll
      for (int nt = 0; nt < 2; ++nt) {
        const short8 bfr = *(const short8*)&x_lds[buf][((w * 2 + nt) * 16 + l) * XS + sk * 32 + q * 8];
#pragma unroll
        for (int mt = 0; mt < 4; ++mt)
          acc2[mt][nt] = __builtin_amdgcn_mfma_f32_16x16x32_bf16(afr[mt], bfr, acc2[mt][nt], 0, 0, 0);
      }
    }
  }

  // ---- epilogue: reduce asum across the 16 lanes of each quad; write partials ----
#pragma unroll
  for (int mt = 0; mt < 4; ++mt)
#pragma unroll
    for (int r = 0; r < 4; ++r) {
      float v = asum_acc[mt][r];
      v += __shfl_xor(v, 1); v += __shfl_xor(v, 2);
      v += __shfl_xor(v, 4); v += __shfl_xor(v, 8);
      if (l == 0) asum_sh[w][mt * 16 + q * 4 + r] = v;
    }
  __syncthreads();
  if (t < NV_K)
    atomicAdd(asum_ws + (size_t)n * NV_K + t,
              asum_sh[0][t] + asum_sh[1][t] + asum_sh[2][t] + asum_sh[3][t]);

  float* vw = vlad_ws + (size_t)n * (NV_K * NV_C);
#pragma unroll
  for (int mt = 0; mt < 4; ++mt)
#pragma unroll
    for (int nt = 0; nt < 2; ++nt)
#pragma unroll
      for (int r = 0; r < 4; ++r)
        atomicAdd(vw + (mt * 16 + q * 4 + r) * NV_C + (w * 2 + nt) * 16 + l, acc2[mt][nt][r]);
}

__global__ __launch_bounds__(256) void netvlad_finalize(
    const float* __restrict__ vlad_ws, const float* __restrict__ asum_ws,
    const float* __restrict__ cent, float* __restrict__ out) {
  __shared__ float v_lds[NV_K * NV_C];  // 32 KB
  __shared__ float red4[256];
  __shared__ float rscale[NV_K];
  __shared__ float gscale_sh;

  const int t = threadIdx.x; const int n = blockIdx.x;
  const float* vw = vlad_ws + (size_t)n * (NV_K * NV_C);

#pragma unroll
  for (int i = 0; i < 8; ++i) {
    int vec = t + i * 256; int k = vec >> 5; int cq = vec & 31;
    float4 ws = *(const float4*)(vw + k * NV_C + cq * 4);
    float4 ce = *(const float4*)(cent + k * NV_C + cq * 4);
    float as = asum_ws[(size_t)n * NV_K + k];
    float4 v;
    v.x = ws.x - as * ce.x; v.y = ws.y - as * ce.y;
    v.z = ws.z - as * ce.z; v.w = ws.w - as * ce.w;
    *(float4*)&v_lds[k * NV_C + cq * 4] = v;
  }
  __syncthreads();

  {  // per-cluster sumsq
    const int k = t >> 2, part = t & 3;
    const float* row = &v_lds[k * NV_C + part * 32];
    float ss = 0.0f;
#pragma unroll
    for (int c = 0; c < 32; ++c) { float v = row[c]; ss += v * v; }
    red4[t] = ss;
  }
  __syncthreads();
  if (t < NV_K) {
    float ss = red4[t * 4] + red4[t * 4 + 1] + red4[t * 4 + 2] + red4[t * 4 + 3];
    rscale[t] = 1.0f / fmaxf(sqrtf(ss), 1e-12f);
  }
  __syncthreads();

  float gp = 0.0f;
#pragma unroll
  for (int i = 0; i < 8; ++i) {
    int vec = t + i * 256; int k = vec >> 5; int cq = vec & 31;
    float4 v = *(const float4*)&v_lds[k * NV_C + cq * 4];
    float rs = rscale[k];
    gp += (v.x * v.x + v.y * v.y + v.z * v.z + v.w * v.w) * rs * rs;
  }
  red4[t] = gp;
  __syncthreads();
  if (t < 64) {
    float s = red4[t] + red4[t + 64] + red4[t + 128] + red4[t + 192];
#pragma unroll
    for (int o = 32; o > 0; o >>= 1) s += __shfl_down(s, o);
    if (t == 0) gscale_sh = 1.0f / fmaxf(sqrtf(s), 1e-12f);
  }
  __syncthreads();
  const float gs = gscale_sh;

#pragma unroll
  for (int i = 0; i < 8; ++i) {
    int vec = t + i * 256; int k = vec >> 5; int cq = vec & 31;
    float4 v = *(const float4*)&v_lds[k * NV_C + cq * 4];
    const float sc = rscale[k] * gs;
    v.x *= sc; v.y *= sc; v.z *= sc; v.w *= sc;
    *(float4*)(out + (size_t)n * (NV_K * NV_C) + k * NV_C + cq * 4) = v;
  }
}

extern "C" void kernel_launch(void* const* d_in, const int* in_sizes, int n_in,
                              void* d_out, int out_size, void* d_ws, size_t ws_size,
                              hipStream_t stream) {
  (void)in_sizes; (void)n_in; (void)out_size; (void)ws_size;
  const float* x      = (const float*)d_in[0];
  const float* conv_w = (const float*)d_in[1];
  const float* cent   = (const float*)d_in[2];
  float* out = (float*)d_out;

  float* vlad_ws = (float*)d_ws;
  float* asum_ws = vlad_ws + (size_t)NV_N * NV_K * NV_C;
  const size_t zbytes = ((size_t)NV_N * NV_K * NV_C + (size_t)NV_N * NV_K) * sizeof(float);
  hipMemsetAsync(d_ws, 0, zbytes, stream);

  hipLaunchKernelGGL(netvlad_main, dim3(NV_N * SCHUNK), dim3(256), 0, stream,
                     x, conv_w, vlad_ws, asum_ws);
  hipLaunchKernelGGL(netvlad_finalize, dim3(NV_N), dim3(256), 0, stream,
                     vlad_ws, asum_ws, cent, out);
}